// Round 12
// baseline (1174.632 us; speedup 1.0000x reference)
//
#include <hip/hip_runtime.h>
#include <math.h>

#define T 65536
#define NCH 32
#define LCHUNK 256        // chunk length
#define CCHUNK 256        // chunks per channel
#define SB 256            // reverb block length (65536 = 256 blocks of 256)
#define NBLK 256
#define VH 8              // damping FIR taps (damp<=0.4: 0.4^8 ~ 6.5e-4)

// ws layout (float offsets).
#define OFS_A  0          // 32*65536: biquad out -> final pre-pan signal (in-place)
#define OFS_B1 2097152    // 32*65536: compressor target per sample
#define OFS_I  4194304    // 32*256*384: per-block group records (12 floats/group, 9 used)
#define OFS_P  7340032    // 32*64 derived params (k_mix reads 38/39)

// ---------------- helpers ----------------

__device__ __forceinline__ float bq_step(const float* b0, const float* b1, const float* b2,
                                         const float* a1, const float* a2,
                                         float* z1, float* z2, float s){
  #pragma unroll
  for (int k=0;k<6;k++){
    float y = fmaf(b0[k], s, z1[k]);
    z1[k] = fmaf(b1[k], s, fmaf(-a1[k], y, z2[k]));
    z2[k] = fmaf(b2[k], s, -a2[k]*y);
    s = y;
  }
  return s;
}

__device__ __forceinline__ void load_coefs(const float* Pc, float* b0, float* b1, float* b2,
                                           float* a1, float* a2){
  #pragma unroll
  for (int k=0;k<6;k++){
    b0[k]=Pc[k]; b1[k]=Pc[6+k]; b2[k]=Pc[12+k]; a1[k]=Pc[18+k]; a2[k]=Pc[24+k];
  }
}

__device__ void shelf_store(double fc, double g, double s, float* PcS, int k){
  double A  = pow(10.0, g/40.0);
  double w  = 2.0*3.14159265358979323846*fc/44100.0;
  double cw = cos(w);
  double al = sin(w)*0.70710678118654752;
  double sq = 2.0*sqrt(A)*al;
  double b0 = A*((A+1.0) + s*(A-1.0)*cw + sq);
  double b1 = -2.0*s*A*((A-1.0) + s*(A+1.0)*cw);
  double b2 = A*((A+1.0) + s*(A-1.0)*cw - sq);
  double a0 = (A+1.0) - s*(A-1.0)*cw + sq;
  double a1 = 2.0*s*((A-1.0) - s*(A+1.0)*cw);
  double a2 = (A+1.0) - s*(A-1.0)*cw - sq;
  PcS[k]    = (float)(b0/a0);
  PcS[6+k]  = (float)(b1/a0);
  PcS[12+k] = (float)(b2/a0);
  PcS[18+k] = (float)(a1/a0);
  PcS[24+k] = (float)(a2/a0);
}

__device__ void peak_store(double fc, double g, double q, float* PcS, int k){
  double A  = pow(10.0, g/40.0);
  double w  = 2.0*3.14159265358979323846*fc/44100.0;
  double cw = cos(w);
  double al = sin(w)/(2.0*q);
  double b0 = 1.0+al*A, b1 = -2.0*cw, b2 = 1.0-al*A;
  double a0 = 1.0+al/A, a1 = -2.0*cw, a2 = 1.0-al/A;
  PcS[k]    = (float)(b0/a0);
  PcS[6+k]  = (float)(b1/a0);
  PcS[12+k] = (float)(b2/a0);
  PcS[18+k] = (float)(a1/a0);
  PcS[24+k] = (float)(a2/a0);
}

// ---------------- fused per-channel pipeline --------------------------------
// R20 = R19 with the front-end memory accesses COALESCED via LDS tiles.
// R18->R19 isolated a ~95-120us thread-count-invariant front-end cost: lane
// stride of 1KB (chunk-per-thread) splits every wave memory op into 64
// cache-line transactions. Fix: 16-sample tiles; cooperative coalesced x
// loads into XS (pad-17 LDS), per-thread compute from LDS, stage ya/Tv to SB,
// cooperative coalesced A/B1 stores. I-record stores stay direct (block-major
// layout is inherently scattered). Arithmetic is op-for-op identical in
// identical order -> bit-identical results. Verb body byte-identical; shared
// memory repacked into one aligned array so front-end staging can alias the
// verb-only regions (all dead until the verb prologue writes them).

__global__ __launch_bounds__(320) void k_main(const float* __restrict__ x,
                                              const float* __restrict__ p,
                                              float* __restrict__ ws,
                                              float* __restrict__ pout){
  const int LC[8] = {1116,1188,1277,1356,1422,1491,1557,1617};
  const int COFF[8] = {0,1116,2304,3581,4937,6359,7850,9407};
  const int LA[4] = {556,441,341,225};
  const int AOFF[4] = {0,556,997,1338};
  int ch = blockIdx.x, tid = threadIdx.x;
  __shared__ __align__(16) float S[15948];
  float* cb   = S;            // 11024
  float* ab   = S + 11024;    // 1563 (pad to 12588)
  float* cHp  = S + 12588;    // 8*264 = 2112
  float* xts  = S + 14700;    // 256
  float* B1p  = S + 14956;    // 2*256 (16B-aligned)
  float* IldS = S + 15468;    // 384 (16B-aligned)
  float* gBp  = S + 15852;    // 2*32
  float* xfer = S + 15916;    // 32
  // front-end scratch (dead once verb starts):
  float* Vls = cb;            // 256*12 = 3072
  float* Zls = cb + 3072;     // 256*12 = 3072
  float* Mls = cb + 6144;     // 144
  float* PcS = cb + 6288;     // 40
  float* XS  = cb + 6328;     // 256*17 = 4352 (x-tile staging, ends 10680)
  float* SBs = S + 11024;     // 256*17 = 4352 (out-tile staging, aliases ab/cH/xts/B1p-head)

  float* Aio = ws + OFS_A + (size_t)ch*T;
  const float* B1c = ws + OFS_B1 + (size_t)ch*T;
  const float* IG  = ws + OFS_I + (size_t)ch*98304;
  const float* pf = p + ch*24;

  // ---------------- stage 0: params ----------------
  if (tid == 0){
    double gain_in = (double)pf[0]*60.0 - 48.0;
    double hp_fc   = (double)pf[1]*350.0;
    double gin = pow(10.0, gain_in/20.0);
    double K = tan(3.14159265358979323846*hp_fc/44100.0);
    double a1=(K-1.0)/(K+1.0), b0=1.0/(1.0+K);
    PcS[0]  = (float)(b0*gin);
    PcS[6]  = (float)(-b0*gin);
    PcS[12] = 0.0f;
    PcS[18] = (float)a1;
    PcS[24] = 0.0f;
  } else if (tid == 1){
    double lp_fc = (double)pf[2]*19000.0 + 3000.0;
    double K = tan(3.14159265358979323846*lp_fc/44100.0);
    double a1=(K-1.0)/(K+1.0), b0=K/(1.0+K);
    PcS[1]  = (float)b0;
    PcS[7]  = (float)b0;
    PcS[13] = 0.0f;
    PcS[19] = (float)a1;
    PcS[25] = 0.0f;
  } else if (tid == 2){
    shelf_store((double)pf[3]*14500.0 + 1500.0, (double)pf[4]*30.0 - 15.0,  1.0, PcS, 2);
  } else if (tid == 3){
    shelf_store((double)pf[5]*420.0 + 30.0,    (double)pf[6]*30.0 - 15.0, -1.0, PcS, 3);
  } else if (tid == 4){
    peak_store((double)pf[7]*6400.0 + 600.0,  (double)pf[8]*30.0 - 15.0,
               (double)pf[9]*2.5 + 0.5, PcS, 4);
  } else if (tid == 5){
    peak_store((double)pf[10]*2300.0 + 200.0, (double)pf[11]*30.0 - 15.0,
               (double)pf[12]*2.5 + 0.5, PcS, 5);
  } else if (tid == 6){
    double c_thr = (double)pf[13]*30.0 - 20.0;
    double c_rat = (double)pf[14]*19.0 + 1.0;
    double c_att = (double)pf[15]*29.0 + 1.0;
    double c_rel = (double)pf[16]*3900.0 + 100.0;
    PcS[30] = (float)c_thr;
    PcS[31] = (float)(1.0 - 1.0/c_rat);
    PcS[32] = (float)exp(-1.0/(c_att*0.001*44100.0));
    PcS[33] = (float)exp(-1.0/(c_rel*0.001*44100.0));
  } else if (tid == 7){
    double fb   = (double)pf[17]*0.28 + 0.7;
    double damp = (double)pf[18]*0.4;
    double wet1 = 3.0*(double)pf[19]*0.5*(1.0+(double)pf[21]);
    double dryg = 2.0*(double)pf[20];
    double gain_out = (double)pf[22]*60.0 - 48.0;
    double gout = pow(10.0, gain_out/20.0);
    double pan  = (double)pf[23]*0.4 + 0.3;
    PcS[34] = (float)fb;
    PcS[35] = (float)damp;
    PcS[36] = (float)(wet1*gout);
    PcS[37] = (float)(dryg*gout/0.015);
    PcS[38] = (float)cos(pan*1.57079632679489662);
    PcS[39] = (float)sin(pan*1.57079632679489662);
  } else if (tid == 8){
    float* po = pout + ch*24;
    po[0]=(float)((double)pf[0]*60.0-48.0);   po[1]=(float)((double)pf[1]*350.0);
    po[2]=(float)((double)pf[2]*19000.0+3000.0); po[3]=(float)((double)pf[3]*14500.0+1500.0);
    po[4]=(float)((double)pf[4]*30.0-15.0);   po[5]=(float)((double)pf[5]*420.0+30.0);
    po[6]=(float)((double)pf[6]*30.0-15.0);   po[7]=(float)((double)pf[7]*6400.0+600.0);
    po[8]=(float)((double)pf[8]*30.0-15.0);   po[9]=(float)((double)pf[9]*2.5+0.5);
    po[10]=(float)((double)pf[10]*2300.0+200.0); po[11]=(float)((double)pf[11]*30.0-15.0);
    po[12]=(float)((double)pf[12]*2.5+0.5);   po[13]=(float)((double)pf[13]*30.0-20.0);
    po[14]=(float)((double)pf[14]*19.0+1.0);  po[15]=(float)((double)pf[15]*29.0+1.0);
    po[16]=(float)((double)pf[16]*3900.0+100.0);
    po[17]=pf[17]; po[18]=pf[18]; po[19]=pf[19]; po[20]=pf[20]; po[21]=pf[21];
    po[22]=(float)((double)pf[22]*60.0-48.0); po[23]=(float)((double)pf[23]*0.4+0.3);
  }
  __syncthreads();

  float fb = PcS[34], damp = PcS[35], wet1 = PcS[36], dryk = PcS[37];
  float aA = PcS[32], aR = PcS[33];
  float thr = PcS[30], rt = PcS[31];
  float kA = 1.0f - aA, kR = 1.0f - aR;
  float omd = 1.0f - damp;
  float b0[6],b1[6],b2[6],a1[6],a2[6];
  if (tid < 268) load_coefs(PcS,b0,b1,b2,a1,a2);
  if (tid < 40) (ws + OFS_P + ch*64)[tid] = PcS[tid];

  const float4* x4 = (const float4*)(x + (size_t)ch*T);

  // ---------------- stage 1: chunk1, coalesced x via XS tiles ----------------
  {
    float z1[6]={0,0,0,0,0,0}, z2[6]={0,0,0,0,0,0};
    if (tid >= 256 && tid < 268){
      int j = tid - CCHUNK;
      if ((j & 1)==0) z1[j>>1]=1.0f; else z2[j>>1]=1.0f;
    }
    for (int tt=0; tt<16; tt++){
      for (int j=tid; j<1024; j+=320){
        int c = j>>2, q = j&3;
        float4 v = x4[c*64 + tt*4 + q];
        float* d = &XS[c*17 + q*4];
        d[0]=v.x; d[1]=v.y; d[2]=v.z; d[3]=v.w;
      }
      __syncthreads();
      if (tid < 256){
        const float* xs = &XS[tid*17];
        #pragma unroll
        for (int w=0;w<16;w++) bq_step(b0,b1,b2,a1,a2,z1,z2,xs[w]);
      } else if (tid < 268){
        #pragma unroll
        for (int w=0;w<16;w++) bq_step(b0,b1,b2,a1,a2,z1,z2,0.0f);
      }
      __syncthreads();
    }
    if (tid < 256){
      #pragma unroll
      for (int k=0;k<6;k++){ Vls[tid*12+2*k]=z1[k]; Vls[tid*12+2*k+1]=z2[k]; }
    } else if (tid < 268){
      int j = tid - CCHUNK;
      #pragma unroll
      for (int k=0;k<6;k++){ Mls[j*12+2*k]=z1[k]; Mls[j*12+2*k+1]=z2[k]; }
    }
  }
  __syncthreads();

  // ---------------- stage 2: chunk2 scan (12-lane shfl, j-ascending) -------
  if (tid < 64){
    int i = tid; bool act = (i < 12);
    float Mr_[12];
    #pragma unroll
    for (int j=0;j<12;j++) Mr_[j] = act ? Mls[j*12+i] : 0.0f;
    float z = 0.0f;
    for (int c=0;c<CCHUNK;c++){
      if (act) Zls[c*12+i] = z;
      float zn = act ? Vls[c*12+i] : 0.0f;
      #pragma unroll
      for (int j=0;j<12;j++) zn = fmaf(Mr_[j], __shfl(z, j), zn);
      z = zn;
    }
  }
  __syncthreads();

  // ---------------- stage 3: chunk3, coalesced x/A/B1 via tiles -------------
  {
    float z1[6], z2[6];
    if (tid < 256){
      #pragma unroll
      for (int k=0;k<6;k++){ z1[k]=Zls[tid*12+2*k]; z2[k]=Zls[tid*12+2*k+1]; }
    }
    float4* Ao4 = (float4*)(ws + OFS_A  + (size_t)ch*T);
    float4* B14 = (float4*)(ws + OFS_B1 + (size_t)ch*T);
    float*  Ig  = ws + OFS_I + (size_t)ch*98304;
    for (int tt=0; tt<16; tt++){
      for (int j=tid; j<1024; j+=320){
        int c = j>>2, q = j&3;
        float4 v = x4[c*64 + tt*4 + q];
        float* d = &XS[c*17 + q*4];
        d[0]=v.x; d[1]=v.y; d[2]=v.z; d[3]=v.w;
      }
      __syncthreads();
      float ya[16], Tv[16];
      if (tid < 256){
        const float* xs = &XS[tid*17];
        #pragma unroll
        for (int w=0;w<16;w++){
          ya[w] = bq_step(b0,b1,b2,a1,a2,z1,z2,xs[w]);
          Tv[w] = fminf(0.0f, (thr - 6.0205999132796239f*log2f(fabsf(ya[w])+1e-6f))*rt);
        }
        // I-records for the tile's 2 groups (direct stores; thread = verb block)
        #pragma unroll
        for (int h=0;h<2;h++){
          const float* tv = &Tv[h*8];
          float bb[9];
          bb[0] = kR*tv[0]; bb[1] = kA*tv[0];
          #pragma unroll
          for (int s=1;s<8;s++){
            float bA = kA*tv[s], bR = kR*tv[s];
            bb[s+1] = fmaf(aA, bb[s], bA);
            #pragma unroll
            for (int j=7;j>=1;j--){
              if (j<=s) bb[j] = fminf(fmaf(aA, bb[j-1], bA), fmaf(aR, bb[j], bR));
            }
            bb[0] = fmaf(aR, bb[0], bR);
          }
          float* ig = Ig + (size_t)tid*384 + (tt*2+h)*12;
          *(float4*)(ig)   = make_float4(bb[0],bb[1],bb[2],bb[3]);
          *(float4*)(ig+4) = make_float4(bb[4],bb[5],bb[6],bb[7]);
          *(float4*)(ig+8) = make_float4(bb[8],0.0f,0.0f,0.0f);
        }
        float* sb = &SBs[tid*17];
        #pragma unroll
        for (int w=0;w<16;w++) sb[w] = ya[w];
      }
      __syncthreads();
      for (int j=tid; j<1024; j+=320){
        int c = j>>2, q = j&3;
        const float* sx = &SBs[c*17 + q*4];
        Ao4[c*64 + tt*4 + q] = make_float4(sx[0],sx[1],sx[2],sx[3]);
      }
      __syncthreads();
      if (tid < 256){
        float* sb = &SBs[tid*17];
        #pragma unroll
        for (int w=0;w<16;w++) sb[w] = Tv[w];
      }
      __syncthreads();
      for (int j=tid; j<1024; j+=320){
        int c = j>>2, q = j&3;
        const float* sx = &SBs[c*17 + q*4];
        B14[c*64 + tt*4 + q] = make_float4(sx[0],sx[1],sx[2],sx[3]);
      }
      // next tile's XS load may overlap B1 store; SBs rewritten only after
      // the next tile's post-load barrier -> safe without extra barrier here
    }
  }
  __syncthreads();   // vmcnt drain: stage-3 global writes visible to verb reads

  // ---------------- verb: verbatim R10 body ----------------
  for (int i=tid;i<11024;i+=320) cb[i]=0.0f;
  for (int i=tid;i<1563;i+=320)  ab[i]=0.0f;
  for (int i=tid;i<8*264;i+=320) cHp[i]=0.0f;
  bool scanw = (tid >= 256);
  int sl = tid - 256;
  // FIR weights damp^d
  float w[VH];
  { float pw = 1.0f;
    #pragma unroll
    for (int d=0;d<VH;d++){ w[d]=pw; pw*=damp; } }
  // scan slopes s_j = aA^j aR^(8-j)
  float sj[9];
  { float pA = 1.0f;
    #pragma unroll
    for (int j=0;j<9;j++){ sj[j]=pA; pA*=aA; }
    float pR = 1.0f;
    #pragma unroll
    for (int j=8;j>=0;j--){ sj[j]*=pR; pR*=aR; } }
  int cbb[8] = {0,0,0,0,0,0,0,0};
  int abb[4] = {0,0,0,0};
  float gcarry = 0.0f;
  float4 iR0, iR1, bR;
  float xv = 0.0f;

  // ---- prologue: IldS=I(0); B1st[0]=t(0), B1st[1]=t(1); regs=I(1); xv=x(0) ----
  if (scanw){
    const float4* isrc = (const float4*)(IG);
    float4* idst = (float4*)IldS;
    idst[sl] = isrc[sl];
    if (sl < 32) idst[64+sl] = isrc[64+sl];
    iR0 = isrc[96+sl];
    if (sl < 32) iR1 = isrc[96+64+sl];
    const float4* bsrc = (const float4*)(B1c);
    ((float4*)B1p)[sl] = bsrc[sl];
    ((float4*)(B1p+256))[sl] = bsrc[64+sl];
  }
  if (tid < 256) xv = Aio[tid];
  __syncthreads();
  if (tid == 256){
    float g = 0.0f;
    for (int m=0;m<32;m++){
      gBp[m] = g;
      const float* Ip = &IldS[m*12];
      float f0=fmaf(sj[0],g,Ip[0]), f1=fmaf(sj[1],g,Ip[1]), f2=fmaf(sj[2],g,Ip[2]);
      float f3=fmaf(sj[3],g,Ip[3]), f4=fmaf(sj[4],g,Ip[4]), f5=fmaf(sj[5],g,Ip[5]);
      float f6=fmaf(sj[6],g,Ip[6]), f7=fmaf(sj[7],g,Ip[7]), f8=fmaf(sj[8],g,Ip[8]);
      g = fminf(fminf(fminf(f0,f1),fminf(f2,f3)),
                fminf(fminf(f4,f5),fminf(fminf(f6,f7),f8)));
    }
    gcarry = g;
  }
  __syncthreads();

  for (int i=0;i<NBLK;i++){
    int t0 = i<<8;
    int p2 = i & 1;
    float xt = 0.0f, acc = 0.0f, a = 0.0f;
    // ---------- phase A (LDS-only) ----------
    if (tid < 256){
      int m = tid>>3, r = tid&7;
      float g = gBp[p2*32+m];
      const float* Bl = B1p + p2*256 + (m<<3);
      float4 q0 = *(const float4*)(Bl);
      float4 q1 = *(const float4*)(Bl+4);
      float tv[8] = {q0.x,q0.y,q0.z,q0.w,q1.x,q1.y,q1.z,q1.w};
      #pragma unroll
      for (int s=0;s<8;s++){
        if (s<=r){
          float tt = tv[s];
          g = fminf(fmaf(aA,g,kA*tt), fmaf(aR,g,kR*tt));
        }
      }
      xt = xv * exp2f(g*0.16609640474436813f) * 0.015f;
      xts[tid] = xt;
      #pragma unroll
      for (int k=0;k<8;k++){
        int idx = cbb[k]+tid; if (idx>=LC[k]) idx-=LC[k];
        float o = cb[COFF[k]+idx];
        cHp[k*264+VH+tid] = omd*o;
        acc += o;
      }
    } else if (i+1 < NBLK){
      // wave4: LDS-write staged regs: IldS = I(i+1); B1st[(i+1)&1] = t(i+1)
      float4* idst = (float4*)IldS;
      idst[sl] = iR0;
      if (sl < 32) idst[64+sl] = iR1;
      if (i >= 1) ((float4*)(B1p + ((i+1)&1)*256))[sl] = bR;
    }
    __syncthreads();
    // ---------- phase B1: issue globals first, then compute ----------
    if (tid < 256){
      if (i+1 < NBLK) xv = Aio[t0+256+tid];    // prefetch next x (drain covered)
      // FIR damping + comb writes
      #pragma unroll
      for (int k=0;k<8;k++){
        float s = 0.0f;
        #pragma unroll
        for (int d=0;d<VH;d++) s = fmaf(w[d], cHp[k*264+VH+tid-d], s);
        int idx = cbb[k]+tid; if (idx>=LC[k]) idx-=LC[k];
        cb[COFF[k]+idx] = fmaf(fb, s, xt);
      }
      // allpass stages 1-3, per-lane registers (slots unique: SB <= L)
      a = acc;
      #pragma unroll
      for (int j=0;j<3;j++){
        int idx = abb[j]+tid; if (idx>=LA[j]) idx-=LA[j];
        float bv = ab[AOFF[j]+idx];
        ab[AOFF[j]+idx] = fmaf(0.5f, bv, a);
        a = bv - a;
      }
      if (tid >= 225) xfer[tid-225] = a;
    } else {
      if (i+2 < NBLK){                         // stage block i+2 into regs
        const float4* isrc = (const float4*)(IG + (size_t)(i+2)*384);
        iR0 = isrc[sl];
        if (sl < 32) iR1 = isrc[64+sl];
        const float4* bsrc = (const float4*)(B1c + (size_t)(i+2)*SB);
        bR = bsrc[sl];
      }
      if (tid == 256 && i+1 < NBLK){           // scan block i+1
        int q = (i+1)&1;
        float g = gcarry;
        #pragma unroll 4
        for (int m=0;m<32;m++){
          gBp[q*32+m] = g;
          const float* Ip = &IldS[m*12];
          float f0=fmaf(sj[0],g,Ip[0]), f1=fmaf(sj[1],g,Ip[1]), f2=fmaf(sj[2],g,Ip[2]);
          float f3=fmaf(sj[3],g,Ip[3]), f4=fmaf(sj[4],g,Ip[4]), f5=fmaf(sj[5],g,Ip[5]);
          float f6=fmaf(sj[6],g,Ip[6]), f7=fmaf(sj[7],g,Ip[7]), f8=fmaf(sj[8],g,Ip[8]);
          g = fminf(fminf(fminf(f0,f1),fminf(f2,f3)),
                    fminf(fminf(f4,f5),fminf(fminf(f6,f7),f8)));
        }
        gcarry = g;
      }
    }
    __syncthreads();
    // ---------- phase B2: allpass stage 4 (L=225) + output ----------
    if (tid < 225){
      int idx = abb[3]+tid; if (idx>=225) idx-=225;
      float bv = ab[AOFF[3]+idx];
      float b  = fmaf(0.5f, bv, a);
      float y  = bv - a;
      Aio[t0+tid] = fmaf(y, wet1, xts[tid]*dryk);
      if (tid < 31){
        float a2v = xfer[tid];             // sample tid+225
        float y2 = b - a2v;
        ab[AOFF[3]+idx] = fmaf(0.5f, b, a2v);
        Aio[t0+225+tid] = fmaf(y2, wet1, xts[225+tid]*dryk);
      } else {
        ab[AOFF[3]+idx] = b;
      }
    } else if (tid >= 232 && tid < 288){
      int q = tid-232; int k = q/7, d = q%7;   // halo: prev block samples 249..255
      cHp[k*264+1+d] = cHp[k*264+257+d];
    }
    #pragma unroll
    for (int k=0;k<8;k++){ cbb[k]+=SB; if (cbb[k]>=LC[k]) cbb[k]-=LC[k]; }
    #pragma unroll
    for (int j=0;j<4;j++){
      abb[j]+=SB;
      if (abb[j]>=LA[j]) abb[j]-=LA[j];
      if (abb[j]>=LA[j]) abb[j]-=LA[j];   // L=225 < SB=256 needs 2nd wrap
    }
    __syncthreads();
  }
}

// ---------------- pan mix ----------------

__global__ void k_mix(const float* __restrict__ ws, float* __restrict__ out){
  int id = blockIdx.x*256 + threadIdx.x;   // 4*65536
  int t = id & (T-1), b = id >> 16;
  const float* Av = ws + OFS_A + (size_t)b*8*T + t;
  const float* P = ws + OFS_P;
  float s0=0.0f, s1=0.0f;
  #pragma unroll
  for (int n=0;n<8;n++){
    float v = Av[(size_t)n*T];
    int ch = b*8+n;
    s0 = fmaf(v, P[ch*64+38], s0);
    s1 = fmaf(v, P[ch*64+39], s1);
  }
  out[b*2*T + t]     = s0;
  out[b*2*T + T + t] = s1;
}

extern "C" void kernel_launch(void* const* d_in, const int* in_sizes, int n_in,
                              void* d_out, int out_size, void* d_ws, size_t ws_size,
                              hipStream_t stream) {
  const float* x = (const float*)d_in[0];
  const float* p = (const float*)d_in[1];
  float* out = (float*)d_out;
  float* ws  = (float*)d_ws;

  k_main<<<NCH, 320, 0, stream>>>(x, p, ws, out + 4*2*T);
  k_mix <<<(4*T)/256, 256, 0, stream>>>(ws, out);
}

// Round 14
// 812.099 us; speedup vs baseline: 1.4464x; 1.4464x over previous
//
#include <hip/hip_runtime.h>
#include <math.h>

#define T 65536
#define NCH 32
#define LCHUNK 256        // chunk length (R19: 512->256 to double front-end waves)
#define CCHUNK 256        // chunks per channel
#define SB 256            // reverb block length (65536 = 256 blocks of 256)
#define NBLK 256
#define VH 8              // damping FIR taps (damp<=0.4: 0.4^8 ~ 6.5e-4)

// ws layout (float offsets).
#define OFS_A  0          // 32*65536: biquad out -> final pre-pan signal (in-place)
#define OFS_B1 2097152    // 32*65536: compressor target per sample
#define OFS_I  4194304    // 32*256*384: per-block group records (12 floats/group, 9 used)
#define OFS_P  7340032    // 32*64 derived params (k_mix reads 38/39)

// ---------------- helpers ----------------

__device__ __forceinline__ float bq_step(const float* b0, const float* b1, const float* b2,
                                         const float* a1, const float* a2,
                                         float* z1, float* z2, float s){
  #pragma unroll
  for (int k=0;k<6;k++){
    float y = fmaf(b0[k], s, z1[k]);
    z1[k] = fmaf(b1[k], s, fmaf(-a1[k], y, z2[k]));
    z2[k] = fmaf(b2[k], s, -a2[k]*y);
    s = y;
  }
  return s;
}

__device__ __forceinline__ void load_coefs(const float* Pc, float* b0, float* b1, float* b2,
                                           float* a1, float* a2){
  #pragma unroll
  for (int k=0;k<6;k++){
    b0[k]=Pc[k]; b1[k]=Pc[6+k]; b2[k]=Pc[12+k]; a1[k]=Pc[18+k]; a2[k]=Pc[24+k];
  }
}

__device__ void shelf_store(double fc, double g, double s, float* PcS, int k){
  double A  = pow(10.0, g/40.0);
  double w  = 2.0*3.14159265358979323846*fc/44100.0;
  double cw = cos(w);
  double al = sin(w)*0.70710678118654752;
  double sq = 2.0*sqrt(A)*al;
  double b0 = A*((A+1.0) + s*(A-1.0)*cw + sq);
  double b1 = -2.0*s*A*((A-1.0) + s*(A+1.0)*cw);
  double b2 = A*((A+1.0) + s*(A-1.0)*cw - sq);
  double a0 = (A+1.0) - s*(A-1.0)*cw + sq;
  double a1 = 2.0*s*((A-1.0) - s*(A+1.0)*cw);
  double a2 = (A+1.0) - s*(A-1.0)*cw - sq;
  PcS[k]    = (float)(b0/a0);
  PcS[6+k]  = (float)(b1/a0);
  PcS[12+k] = (float)(b2/a0);
  PcS[18+k] = (float)(a1/a0);
  PcS[24+k] = (float)(a2/a0);
}

__device__ void peak_store(double fc, double g, double q, float* PcS, int k){
  double A  = pow(10.0, g/40.0);
  double w  = 2.0*3.14159265358979323846*fc/44100.0;
  double cw = cos(w);
  double al = sin(w)/(2.0*q);
  double b0 = 1.0+al*A, b1 = -2.0*cw, b2 = 1.0-al*A;
  double a0 = 1.0+al/A, a1 = -2.0*cw, a2 = 1.0-al/A;
  PcS[k]    = (float)(b0/a0);
  PcS[6+k]  = (float)(b1/a0);
  PcS[12+k] = (float)(b2/a0);
  PcS[18+k] = (float)(a1/a0);
  PcS[24+k] = (float)(a2/a0);
}

// ---------------- fused per-channel pipeline --------------------------------
// R22 = exact R19 resubmit (session best, 816.6us measured in Round 11;
// k_main 796-805). Round 13's submission of this same code hit an infra
// failure ("container failed twice") -- same signature as R5/R9, both of
// which passed on identical resubmit. Front-end: one block per channel runs
// params (threads 0-8) -> chunk1 (268 threads, V/M to LDS) -> chunk2
// (12-lane shfl scan) -> chunk3 (256 threads, A/B1/I to global) -> verbatim
// R10 verb body. Front-end scratch aliases into cb (zeroed before verb).

__global__ __launch_bounds__(320) void k_main(const float* __restrict__ x,
                                              const float* __restrict__ p,
                                              float* __restrict__ ws,
                                              float* __restrict__ pout){
  const int LC[8] = {1116,1188,1277,1356,1422,1491,1557,1617};
  const int COFF[8] = {0,1116,2304,3581,4937,6359,7850,9407};
  const int LA[4] = {556,441,341,225};
  const int AOFF[4] = {0,556,997,1338};
  int ch = blockIdx.x, tid = threadIdx.x;
  __shared__ float cb[11024];
  __shared__ float ab[1563];
  __shared__ float cH[8][264];     // [k][8 halo + 256]
  __shared__ float xts[256];
  __shared__ float B1st[2][256];   // target staging, dbuf
  __shared__ float IldS[384];      // 32 group records x 12
  __shared__ float gB[2][32];      // group-boundary g, dbuf
  __shared__ float xfer[32];       // stage-3 outputs for samples 225..255
  // front-end scratch aliased into cb (zeroed later): 256-chunk layout
  float* Vls = cb;                 // 256*12 = 3072
  float* Zls = cb + 3072;          // 256*12 = 3072
  float* Mls = cb + 6144;          // 12*12  = 144
  float* PcS = cb + 6288;          // 40     (ends 6328 < 11024)

  float* Aio = ws + OFS_A + (size_t)ch*T;
  const float* B1c = ws + OFS_B1 + (size_t)ch*T;
  const float* IG  = ws + OFS_I + (size_t)ch*98304;
  const float* pf = p + ch*24;

  // ---------------- stage 0: params (verbatim k_params math) ----------------
  if (tid == 0){
    double gain_in = (double)pf[0]*60.0 - 48.0;
    double hp_fc   = (double)pf[1]*350.0;
    double gin = pow(10.0, gain_in/20.0);
    double K = tan(3.14159265358979323846*hp_fc/44100.0);
    double a1=(K-1.0)/(K+1.0), b0=1.0/(1.0+K);
    PcS[0]  = (float)(b0*gin);
    PcS[6]  = (float)(-b0*gin);
    PcS[12] = 0.0f;
    PcS[18] = (float)a1;
    PcS[24] = 0.0f;
  } else if (tid == 1){
    double lp_fc = (double)pf[2]*19000.0 + 3000.0;
    double K = tan(3.14159265358979323846*lp_fc/44100.0);
    double a1=(K-1.0)/(K+1.0), b0=K/(1.0+K);
    PcS[1]  = (float)b0;
    PcS[7]  = (float)b0;
    PcS[13] = 0.0f;
    PcS[19] = (float)a1;
    PcS[25] = 0.0f;
  } else if (tid == 2){
    shelf_store((double)pf[3]*14500.0 + 1500.0, (double)pf[4]*30.0 - 15.0,  1.0, PcS, 2);
  } else if (tid == 3){
    shelf_store((double)pf[5]*420.0 + 30.0,    (double)pf[6]*30.0 - 15.0, -1.0, PcS, 3);
  } else if (tid == 4){
    peak_store((double)pf[7]*6400.0 + 600.0,  (double)pf[8]*30.0 - 15.0,
               (double)pf[9]*2.5 + 0.5, PcS, 4);
  } else if (tid == 5){
    peak_store((double)pf[10]*2300.0 + 200.0, (double)pf[11]*30.0 - 15.0,
               (double)pf[12]*2.5 + 0.5, PcS, 5);
  } else if (tid == 6){
    double c_thr = (double)pf[13]*30.0 - 20.0;
    double c_rat = (double)pf[14]*19.0 + 1.0;
    double c_att = (double)pf[15]*29.0 + 1.0;
    double c_rel = (double)pf[16]*3900.0 + 100.0;
    PcS[30] = (float)c_thr;
    PcS[31] = (float)(1.0 - 1.0/c_rat);
    PcS[32] = (float)exp(-1.0/(c_att*0.001*44100.0));
    PcS[33] = (float)exp(-1.0/(c_rel*0.001*44100.0));
  } else if (tid == 7){
    double fb   = (double)pf[17]*0.28 + 0.7;
    double damp = (double)pf[18]*0.4;
    double wet1 = 3.0*(double)pf[19]*0.5*(1.0+(double)pf[21]);
    double dryg = 2.0*(double)pf[20];
    double gain_out = (double)pf[22]*60.0 - 48.0;
    double gout = pow(10.0, gain_out/20.0);
    double pan  = (double)pf[23]*0.4 + 0.3;
    PcS[34] = (float)fb;
    PcS[35] = (float)damp;
    PcS[36] = (float)(wet1*gout);
    PcS[37] = (float)(dryg*gout/0.015);
    PcS[38] = (float)cos(pan*1.57079632679489662);
    PcS[39] = (float)sin(pan*1.57079632679489662);
  } else if (tid == 8){
    float* po = pout + ch*24;
    po[0]=(float)((double)pf[0]*60.0-48.0);   po[1]=(float)((double)pf[1]*350.0);
    po[2]=(float)((double)pf[2]*19000.0+3000.0); po[3]=(float)((double)pf[3]*14500.0+1500.0);
    po[4]=(float)((double)pf[4]*30.0-15.0);   po[5]=(float)((double)pf[5]*420.0+30.0);
    po[6]=(float)((double)pf[6]*30.0-15.0);   po[7]=(float)((double)pf[7]*6400.0+600.0);
    po[8]=(float)((double)pf[8]*30.0-15.0);   po[9]=(float)((double)pf[9]*2.5+0.5);
    po[10]=(float)((double)pf[10]*2300.0+200.0); po[11]=(float)((double)pf[11]*30.0-15.0);
    po[12]=(float)((double)pf[12]*2.5+0.5);   po[13]=(float)((double)pf[13]*30.0-20.0);
    po[14]=(float)((double)pf[14]*19.0+1.0);  po[15]=(float)((double)pf[15]*29.0+1.0);
    po[16]=(float)((double)pf[16]*3900.0+100.0);
    po[17]=pf[17]; po[18]=pf[18]; po[19]=pf[19]; po[20]=pf[20]; po[21]=pf[21];
    po[22]=(float)((double)pf[22]*60.0-48.0); po[23]=(float)((double)pf[23]*0.4+0.3);
  }
  __syncthreads();

  // params to registers (all threads) + global P for k_mix
  float fb = PcS[34], damp = PcS[35], wet1 = PcS[36], dryk = PcS[37];
  float aA = PcS[32], aR = PcS[33];
  float thr = PcS[30], rt = PcS[31];
  float kA = 1.0f - aA, kR = 1.0f - aR;
  float omd = 1.0f - damp;
  float b0[6],b1[6],b2[6],a1[6],a2[6];
  if (tid < 268) load_coefs(PcS,b0,b1,b2,a1,a2);
  if (tid < 40) (ws + OFS_P + ch*64)[tid] = PcS[tid];

  // ---------------- stage 1: chunk1 (V to LDS; M task on threads 256-267) ---
  if (tid < 268){
    float z1[6]={0,0,0,0,0,0}, z2[6]={0,0,0,0,0,0};
    if (tid < CCHUNK){
      const float4* xp = (const float4*)(x + ch*T + tid*LCHUNK);
      for (int j=0;j<LCHUNK/4;j++){
        float4 v = xp[j];
        bq_step(b0,b1,b2,a1,a2,z1,z2,v.x);
        bq_step(b0,b1,b2,a1,a2,z1,z2,v.y);
        bq_step(b0,b1,b2,a1,a2,z1,z2,v.z);
        bq_step(b0,b1,b2,a1,a2,z1,z2,v.w);
      }
      #pragma unroll
      for (int k=0;k<6;k++){ Vls[tid*12+2*k]=z1[k]; Vls[tid*12+2*k+1]=z2[k]; }
    } else {
      int j = tid - CCHUNK;                  // unit state index 0..11
      if ((j & 1)==0) z1[j>>1]=1.0f; else z2[j>>1]=1.0f;
      for (int t=0;t<LCHUNK;t++) bq_step(b0,b1,b2,a1,a2,z1,z2,0.0f);
      #pragma unroll
      for (int k=0;k<6;k++){ Mls[j*12+2*k]=z1[k]; Mls[j*12+2*k+1]=z2[k]; }
    }
  }
  __syncthreads();

  // ---------------- stage 2: chunk2 scan (12-lane shfl, j-ascending) -------
  if (tid < 64){
    int i = tid; bool act = (i < 12);
    float Mr_[12];
    #pragma unroll
    for (int j=0;j<12;j++) Mr_[j] = act ? Mls[j*12+i] : 0.0f;
    float z = 0.0f;
    for (int c=0;c<CCHUNK;c++){
      if (act) Zls[c*12+i] = z;
      float zn = act ? Vls[c*12+i] : 0.0f;
      #pragma unroll
      for (int j=0;j<12;j++) zn = fmaf(Mr_[j], __shfl(z, j), zn);
      z = zn;
    }
  }
  __syncthreads();

  // ---------------- stage 3: chunk3 (A, B1, I to global) ----------------
  if (tid < CCHUNK){
    int c = tid;
    float z1[6], z2[6];
    #pragma unroll
    for (int k=0;k<6;k++){ z1[k]=Zls[c*12+2*k]; z2[k]=Zls[c*12+2*k+1]; }
    const float4* xp = (const float4*)(x + ch*T + c*LCHUNK);
    float4* Ao  = (float4*)(ws + OFS_A  + (size_t)ch*T + c*LCHUNK);
    float4* B1o = (float4*)(ws + OFS_B1 + (size_t)ch*T + c*LCHUNK);
    float*  Ig  = ws + OFS_I + (size_t)ch*98304;
    for (int gg=0; gg<LCHUNK/8; gg++){
      float4 v0 = xp[2*gg], v1 = xp[2*gg+1];
      float ya[8], Tv[8];
      ya[0]=bq_step(b0,b1,b2,a1,a2,z1,z2,v0.x);
      ya[1]=bq_step(b0,b1,b2,a1,a2,z1,z2,v0.y);
      ya[2]=bq_step(b0,b1,b2,a1,a2,z1,z2,v0.z);
      ya[3]=bq_step(b0,b1,b2,a1,a2,z1,z2,v0.w);
      ya[4]=bq_step(b0,b1,b2,a1,a2,z1,z2,v1.x);
      ya[5]=bq_step(b0,b1,b2,a1,a2,z1,z2,v1.y);
      ya[6]=bq_step(b0,b1,b2,a1,a2,z1,z2,v1.z);
      ya[7]=bq_step(b0,b1,b2,a1,a2,z1,z2,v1.w);
      #pragma unroll
      for (int s=0;s<8;s++)
        Tv[s] = fminf(0.0f, (thr - 6.0205999132796239f*log2f(fabsf(ya[s])+1e-6f))*rt);
      Ao[2*gg]   = make_float4(ya[0],ya[1],ya[2],ya[3]);
      Ao[2*gg+1] = make_float4(ya[4],ya[5],ya[6],ya[7]);
      B1o[2*gg]   = make_float4(Tv[0],Tv[1],Tv[2],Tv[3]);
      B1o[2*gg+1] = make_float4(Tv[4],Tv[5],Tv[6],Tv[7]);
      // DP: compose 8 min-affine steps
      float bb[9];
      bb[0] = kR*Tv[0]; bb[1] = kA*Tv[0];
      #pragma unroll
      for (int s=1;s<8;s++){
        float bA = kA*Tv[s], bR = kR*Tv[s];
        bb[s+1] = fmaf(aA, bb[s], bA);
        #pragma unroll
        for (int j=7;j>=1;j--){
          if (j<=s) bb[j] = fminf(fmaf(aA, bb[j-1], bA), fmaf(aR, bb[j], bR));
        }
        bb[0] = fmaf(aR, bb[0], bR);
      }
      int G = c*(LCHUNK/8) + gg;             // global group index
      float* ig = Ig + (G>>5)*384 + (G&31)*12;
      *(float4*)(ig)   = make_float4(bb[0],bb[1],bb[2],bb[3]);
      *(float4*)(ig+4) = make_float4(bb[4],bb[5],bb[6],bb[7]);
      *(float4*)(ig+8) = make_float4(bb[8],0.0f,0.0f,0.0f);
    }
  }
  __syncthreads();   // vmcnt drain: stage-3 global writes visible to verb reads

  // ---------------- verb: verbatim R10 body ----------------
  for (int i=tid;i<11024;i+=320) cb[i]=0.0f;
  for (int i=tid;i<1563;i+=320)  ab[i]=0.0f;
  for (int i=tid;i<8*264;i+=320) ((float*)cH)[i]=0.0f;
  bool scanw = (tid >= 256);
  int sl = tid - 256;
  // FIR weights damp^d
  float w[VH];
  { float pw = 1.0f;
    #pragma unroll
    for (int d=0;d<VH;d++){ w[d]=pw; pw*=damp; } }
  // scan slopes s_j = aA^j aR^(8-j)
  float sj[9];
  { float pA = 1.0f;
    #pragma unroll
    for (int j=0;j<9;j++){ sj[j]=pA; pA*=aA; }
    float pR = 1.0f;
    #pragma unroll
    for (int j=8;j>=0;j--){ sj[j]*=pR; pR*=aR; } }
  int cbb[8] = {0,0,0,0,0,0,0,0};
  int abb[4] = {0,0,0,0};
  float gcarry = 0.0f;
  float4 iR0, iR1, bR;
  float xv = 0.0f;

  // ---- prologue: IldS=I(0); B1st[0]=t(0), B1st[1]=t(1); regs=I(1); xv=x(0) ----
  if (scanw){
    const float4* isrc = (const float4*)(IG);
    float4* idst = (float4*)IldS;
    idst[sl] = isrc[sl];
    if (sl < 32) idst[64+sl] = isrc[64+sl];
    iR0 = isrc[96+sl];
    if (sl < 32) iR1 = isrc[96+64+sl];
    const float4* bsrc = (const float4*)(B1c);
    ((float4*)B1st[0])[sl] = bsrc[sl];
    ((float4*)B1st[1])[sl] = bsrc[64+sl];
  }
  if (tid < 256) xv = Aio[tid];
  __syncthreads();
  if (tid == 256){
    float g = 0.0f;
    for (int m=0;m<32;m++){
      gB[0][m] = g;
      const float* Ip = &IldS[m*12];
      float f0=fmaf(sj[0],g,Ip[0]), f1=fmaf(sj[1],g,Ip[1]), f2=fmaf(sj[2],g,Ip[2]);
      float f3=fmaf(sj[3],g,Ip[3]), f4=fmaf(sj[4],g,Ip[4]), f5=fmaf(sj[5],g,Ip[5]);
      float f6=fmaf(sj[6],g,Ip[6]), f7=fmaf(sj[7],g,Ip[7]), f8=fmaf(sj[8],g,Ip[8]);
      g = fminf(fminf(fminf(f0,f1),fminf(f2,f3)),
                fminf(fminf(f4,f5),fminf(fminf(f6,f7),f8)));
    }
    gcarry = g;
  }
  __syncthreads();

  for (int i=0;i<NBLK;i++){
    int t0 = i<<8;
    int p2 = i & 1;
    float xt = 0.0f, acc = 0.0f, a = 0.0f;
    // ---------- phase A (LDS-only) ----------
    if (tid < 256){
      int m = tid>>3, r = tid&7;
      float g = gB[p2][m];
      const float* Bl = B1st[p2] + (m<<3);
      float4 q0 = *(const float4*)(Bl);
      float4 q1 = *(const float4*)(Bl+4);
      float tv[8] = {q0.x,q0.y,q0.z,q0.w,q1.x,q1.y,q1.z,q1.w};
      #pragma unroll
      for (int s=0;s<8;s++){
        if (s<=r){
          float tt = tv[s];
          g = fminf(fmaf(aA,g,kA*tt), fmaf(aR,g,kR*tt));
        }
      }
      xt = xv * exp2f(g*0.16609640474436813f) * 0.015f;
      xts[tid] = xt;
      #pragma unroll
      for (int k=0;k<8;k++){
        int idx = cbb[k]+tid; if (idx>=LC[k]) idx-=LC[k];
        float o = cb[COFF[k]+idx];
        cH[k][VH+tid] = omd*o;
        acc += o;
      }
    } else if (i+1 < NBLK){
      // wave4: LDS-write staged regs: IldS = I(i+1); B1st[(i+1)&1] = t(i+1)
      float4* idst = (float4*)IldS;
      idst[sl] = iR0;
      if (sl < 32) idst[64+sl] = iR1;
      if (i >= 1) ((float4*)B1st[(i+1)&1])[sl] = bR;
    }
    __syncthreads();
    // ---------- phase B1: issue globals first, then compute ----------
    if (tid < 256){
      if (i+1 < NBLK) xv = Aio[t0+256+tid];    // prefetch next x (drain covered)
      // FIR damping + comb writes
      #pragma unroll
      for (int k=0;k<8;k++){
        float s = 0.0f;
        #pragma unroll
        for (int d=0;d<VH;d++) s = fmaf(w[d], cH[k][VH+tid-d], s);
        int idx = cbb[k]+tid; if (idx>=LC[k]) idx-=LC[k];
        cb[COFF[k]+idx] = fmaf(fb, s, xt);
      }
      // allpass stages 1-3, per-lane registers (slots unique: SB <= L)
      a = acc;
      #pragma unroll
      for (int j=0;j<3;j++){
        int idx = abb[j]+tid; if (idx>=LA[j]) idx-=LA[j];
        float bv = ab[AOFF[j]+idx];
        ab[AOFF[j]+idx] = fmaf(0.5f, bv, a);
        a = bv - a;
      }
      if (tid >= 225) xfer[tid-225] = a;
    } else {
      if (i+2 < NBLK){                         // stage block i+2 into regs
        const float4* isrc = (const float4*)(IG + (size_t)(i+2)*384);
        iR0 = isrc[sl];
        if (sl < 32) iR1 = isrc[64+sl];
        const float4* bsrc = (const float4*)(B1c + (size_t)(i+2)*SB);
        bR = bsrc[sl];
      }
      if (tid == 256 && i+1 < NBLK){           // scan block i+1
        int q = (i+1)&1;
        float g = gcarry;
        #pragma unroll 4
        for (int m=0;m<32;m++){
          gB[q][m] = g;
          const float* Ip = &IldS[m*12];
          float f0=fmaf(sj[0],g,Ip[0]), f1=fmaf(sj[1],g,Ip[1]), f2=fmaf(sj[2],g,Ip[2]);
          float f3=fmaf(sj[3],g,Ip[3]), f4=fmaf(sj[4],g,Ip[4]), f5=fmaf(sj[5],g,Ip[5]);
          float f6=fmaf(sj[6],g,Ip[6]), f7=fmaf(sj[7],g,Ip[7]), f8=fmaf(sj[8],g,Ip[8]);
          g = fminf(fminf(fminf(f0,f1),fminf(f2,f3)),
                    fminf(fminf(f4,f5),fminf(fminf(f6,f7),f8)));
        }
        gcarry = g;
      }
    }
    __syncthreads();
    // ---------- phase B2: allpass stage 4 (L=225) + output ----------
    if (tid < 225){
      int idx = abb[3]+tid; if (idx>=225) idx-=225;
      float bv = ab[AOFF[3]+idx];
      float b  = fmaf(0.5f, bv, a);
      float y  = bv - a;
      Aio[t0+tid] = fmaf(y, wet1, xts[tid]*dryk);
      if (tid < 31){
        float a2v = xfer[tid];             // sample tid+225
        float y2 = b - a2v;
        ab[AOFF[3]+idx] = fmaf(0.5f, b, a2v);
        Aio[t0+225+tid] = fmaf(y2, wet1, xts[225+tid]*dryk);
      } else {
        ab[AOFF[3]+idx] = b;
      }
    } else if (tid >= 232 && tid < 288){
      int q = tid-232; int k = q/7, d = q%7;   // halo: prev block samples 249..255
      cH[k][1+d] = cH[k][257+d];
    }
    #pragma unroll
    for (int k=0;k<8;k++){ cbb[k]+=SB; if (cbb[k]>=LC[k]) cbb[k]-=LC[k]; }
    #pragma unroll
    for (int j=0;j<4;j++){
      abb[j]+=SB;
      if (abb[j]>=LA[j]) abb[j]-=LA[j];
      if (abb[j]>=LA[j]) abb[j]-=LA[j];   // L=225 < SB=256 needs 2nd wrap
    }
    __syncthreads();
  }
}

// ---------------- pan mix ----------------

__global__ void k_mix(const float* __restrict__ ws, float* __restrict__ out){
  int id = blockIdx.x*256 + threadIdx.x;   // 4*65536
  int t = id & (T-1), b = id >> 16;
  const float* Av = ws + OFS_A + (size_t)b*8*T + t;
  const float* P = ws + OFS_P;
  float s0=0.0f, s1=0.0f;
  #pragma unroll
  for (int n=0;n<8;n++){
    float v = Av[(size_t)n*T];
    int ch = b*8+n;
    s0 = fmaf(v, P[ch*64+38], s0);
    s1 = fmaf(v, P[ch*64+39], s1);
  }
  out[b*2*T + t]     = s0;
  out[b*2*T + T + t] = s1;
}

extern "C" void kernel_launch(void* const* d_in, const int* in_sizes, int n_in,
                              void* d_out, int out_size, void* d_ws, size_t ws_size,
                              hipStream_t stream) {
  const float* x = (const float*)d_in[0];
  const float* p = (const float*)d_in[1];
  float* out = (float*)d_out;
  float* ws  = (float*)d_ws;

  k_main<<<NCH, 320, 0, stream>>>(x, p, ws, out + 4*2*T);
  k_mix <<<(4*T)/256, 256, 0, stream>>>(ws, out);
}